// Round 1
// baseline (510.628 us; speedup 1.0000x reference)
//
#include <hip/hip_runtime.h>
#include <math.h>

#define B_    20000
#define K_    32
#define DIM_  256
#define H_    128

__device__ __forceinline__ float wave_reduce_sum(float v) {
    #pragma unroll
    for (int m = 32; m >= 1; m >>= 1) v += __shfl_xor(v, m, 64);
    return v;
}

__device__ __forceinline__ float dot4(float4 a, float4 b) {
    return a.x * b.x + a.y * b.y + a.z * b.z + a.w * b.w;
}

// v12[0..255]   = v1[d] = sum_h a[h]     * W[h,d]
// v12[256..511] = v2[d] = sum_h a[128+h] * W[h,d]
__global__ void precompute_v12(const float* __restrict__ W,
                               const float* __restrict__ a,
                               float* __restrict__ v12) {
    int d = blockIdx.x * blockDim.x + threadIdx.x;
    if (d >= DIM_) return;
    float acc1 = 0.f, acc2 = 0.f;
    for (int h = 0; h < H_; ++h) {
        float w = W[h * DIM_ + d];
        acc1 += a[h] * w;
        acc2 += a[H_ + h] * w;
    }
    v12[d] = acc1;
    v12[DIM_ + d] = acc2;
}

__launch_bounds__(256)
__global__ void gat_main(const int* __restrict__ u,
                         const int* __restrict__ t_idx,
                         const int* __restrict__ n_idx,
                         const float* __restrict__ ent,
                         const float* __restrict__ usr,
                         const float* __restrict__ W,
                         const float* __restrict__ v12,
                         float* __restrict__ out) {
    const int b    = blockIdx.x;
    const int tid  = threadIdx.x;
    const int wave = tid >> 6;
    const int lane = tid & 63;

    __shared__ float xn_s[K_][DIM_];   // scaled neighbor rows (32 KB)
    __shared__ float scr_s[K_];        // leaky-relu'd scores
    __shared__ float alpha_s[K_];      // softmax weights
    __shared__ float uc_s[H_];         // scale_u * (usr[h] + usr[h+128])
    __shared__ float red_s[4];

    // Per-lane fragments of v1, v2 (register-resident for all phases)
    const float4 v1_4 = ((const float4*)v12)[lane];
    const float4 v2_4 = ((const float4*)(v12 + DIM_))[lane];

    // ---- Phase A: target row, s0 = scale_t * (raw_t . v1) ----
    // (all 4 waves compute redundantly; loads hit L1)
    {
        // nothing
    }
    const int t = t_idx[b];
    float4 t4 = ((const float4*)(ent + (size_t)t * DIM_))[lane];
    float ss_t = wave_reduce_sum(dot4(t4, t4));
    float scl_t = fminf(1.0f, 1.0f / fmaxf(sqrtf(ss_t), 1e-12f));
    float s0 = scl_t * wave_reduce_sum(dot4(t4, v1_4));

    // ---- Phase E (early): user vector -> uc_s ----
    const int uid = u[b];
    float4 u4 = ((const float4*)(usr + (size_t)uid * DIM_))[lane];
    float ss_u = wave_reduce_sum(dot4(u4, u4));
    float scl_u = fminf(1.0f, 1.0f / fmaxf(sqrtf(ss_u), 1e-12f));
    // lanes 0..31 hold d=4*lane..4*lane+3 (<128); lane+32 holds d+128
    float px = __shfl(u4.x, lane + 32);
    float py = __shfl(u4.y, lane + 32);
    float pz = __shfl(u4.z, lane + 32);
    float pw = __shfl(u4.w, lane + 32);
    if (wave == 0 && lane < 32) {
        float4 uc4;
        uc4.x = scl_u * (u4.x + px);
        uc4.y = scl_u * (u4.y + py);
        uc4.z = scl_u * (u4.z + pz);
        uc4.w = scl_u * (u4.w + pw);
        ((float4*)uc_s)[lane] = uc4;
    }

    // ---- Phase B: neighbors (8 per wave) ----
    for (int kk = 0; kk < 8; ++kk) {
        const int k   = wave * 8 + kk;
        const int idx = n_idx[b * K_ + k];
        float4 e4 = ((const float4*)(ent + (size_t)idx * DIM_))[lane];
        float ssk = wave_reduce_sum(dot4(e4, e4));
        float sk  = fminf(1.0f, 1.0f / fmaxf(sqrtf(ssk), 1e-12f));
        float dv2 = wave_reduce_sum(dot4(e4, v2_4));
        float4 xs;
        xs.x = e4.x * sk; xs.y = e4.y * sk; xs.z = e4.z * sk; xs.w = e4.w * sk;
        ((float4*)xn_s[k])[lane] = xs;
        if (lane == 0) {
            float sc = s0 + sk * dv2;
            scr_s[k] = (sc >= 0.f) ? sc : 0.2f * sc;   // leaky relu, slope 0.2
        }
    }

    __syncthreads();

    // ---- Phase C: softmax over 32 neighbors (lanes 0..31 of wave 0) ----
    if (tid < 32) {
        float e = scr_s[tid];
        float mx = e;
        #pragma unroll
        for (int m = 16; m >= 1; m >>= 1) mx = fmaxf(mx, __shfl_xor(mx, m, 64));
        float ex = expf(e - mx);
        float sm = ex;
        #pragma unroll
        for (int m = 16; m >= 1; m >>= 1) sm += __shfl_xor(sm, m, 64);
        alpha_s[tid] = ex / sm;
    }
    __syncthreads();

    // ---- Phase D: m[d] = sum_k alpha_k * xn_s[k][d]  (thread d = tid) ----
    float m_d = 0.f;
    #pragma unroll
    for (int k = 0; k < K_; ++k) m_d += alpha_s[k] * xn_s[k][tid];

    // ---- Phase F: (uc @ W)[d], then uv = sum_d m[d]*(uc@W)[d] ----
    const float* wcol = W + tid;
    float acc = 0.f;
    #pragma unroll 4
    for (int h = 0; h < H_; ++h) acc += uc_s[h] * wcol[(size_t)h * DIM_];

    float p = wave_reduce_sum(acc * m_d);
    if (lane == 0) red_s[wave] = p;
    __syncthreads();
    if (tid == 0) {
        float uv = red_s[0] + red_s[1] + red_s[2] + red_s[3];
        out[b] = 1.0f / (1.0f + expf(-uv));
    }
}

extern "C" void kernel_launch(void* const* d_in, const int* in_sizes, int n_in,
                              void* d_out, int out_size, void* d_ws, size_t ws_size,
                              hipStream_t stream) {
    const int*   u     = (const int*)d_in[0];
    const int*   t_idx = (const int*)d_in[1];
    const int*   n_idx = (const int*)d_in[2];
    const float* ent   = (const float*)d_in[3];
    const float* usr   = (const float*)d_in[4];
    const float* W     = (const float*)d_in[5];
    const float* a     = (const float*)d_in[6];
    float*       out   = (float*)d_out;
    float*       v12   = (float*)d_ws;   // 512 floats

    hipLaunchKernelGGL(precompute_v12, dim3(1), dim3(256), 0, stream, W, a, v12);
    hipLaunchKernelGGL(gat_main, dim3(B_), dim3(256), 0, stream,
                       u, t_idx, n_idx, ent, usr, W, v12, out);
}

// Round 2
// 476.336 us; speedup vs baseline: 1.0720x; 1.0720x over previous
//
#include <hip/hip_runtime.h>
#include <math.h>

#define B_    20000
#define K_    32
#define DIM_  256
#define H_    128
#define NENT_ 100000

typedef unsigned int   uint_t;
typedef unsigned short ushort_t;

__device__ __forceinline__ float dot4(float4 a, float4 b) {
    return a.x * b.x + a.y * b.y + a.z * b.z + a.w * b.w;
}

__device__ __forceinline__ float wred64(float v) {
    #pragma unroll
    for (int m = 32; m >= 1; m >>= 1) v += __shfl_xor(v, m, 64);
    return v;
}

__device__ __forceinline__ ushort_t f2bf(float f) {
    uint_t x = __float_as_uint(f);
    uint_t r = (x + 0x7fffu + ((x >> 16) & 1u)) >> 16;   // RNE
    return (ushort_t)r;
}

// ============================================================================
// proj_kernel: per-entity scale + P[e][h] = scale_e * sum_d ent[e][d]*W[h][d]
// (bf16 out) + sc1[e] = a[:H].P[e], sc2[e] = a[H:].P[e]
// Block tile: 64 entities x 128 h; thread micro-tile 4e x 8h; d-chunks of 32.
// LDS XOR-swizzled so compute ds_read_b128 is conflict-free.
// ============================================================================
__launch_bounds__(256)
__global__ void proj_kernel(const float* __restrict__ ent,
                            const float* __restrict__ Wm,
                            const float* __restrict__ av,
                            float* __restrict__ sc1,
                            float* __restrict__ sc2,
                            ushort_t* __restrict__ P) {
    __shared__ float Xs[64 * 32];     // 8 KB
    __shared__ float Ws[128 * 32];    // 16 KB
    __shared__ float scale_s[64];
    __shared__ float a_s[2 * H_];

    const int t  = threadIdx.x;
    const int e0 = blockIdx.x * 64;
    const int te = t >> 4;    // 0..15 -> entities 4*te..4*te+3
    const int th = t & 15;    // 0..15 -> h 8*th..8*th+7

    a_s[t] = av[t];

    const int xr  = t >> 3;   // 0..31
    const int xc4 = t & 7;    // float4 col within 32-float chunk

    const float* xb0 = ent + (size_t)min(e0 + xr,      NENT_ - 1) * DIM_;
    const float* xb1 = ent + (size_t)min(e0 + xr + 32, NENT_ - 1) * DIM_;

    float ssq0 = 0.f, ssq1 = 0.f;
    float C[4][8];
    #pragma unroll
    for (int i = 0; i < 4; ++i)
        #pragma unroll
        for (int j = 0; j < 8; ++j) C[i][j] = 0.f;

    for (int dc = 0; dc < 8; ++dc) {
        // ---- global loads (coalesced) ----
        float4 xv0 = ((const float4*)(xb0 + dc * 32))[xc4];
        float4 xv1 = ((const float4*)(xb1 + dc * 32))[xc4];
        float4 wv[4];
        #pragma unroll
        for (int i = 0; i < 4; ++i)
            wv[i] = ((const float4*)(Wm + (size_t)(xr + 32 * i) * DIM_ + dc * 32))[xc4];
        ssq0 += dot4(xv0, xv0);
        ssq1 += dot4(xv1, xv1);

        __syncthreads();   // previous compute done reading LDS
        ((float4*)Xs)[xr * 8        + (xc4 ^ ((xr >> 2) & 7))]        = xv0;
        ((float4*)Xs)[(xr + 32) * 8 + (xc4 ^ (((xr + 32) >> 2) & 7))] = xv1;
        #pragma unroll
        for (int i = 0; i < 4; ++i) {
            int r = xr + 32 * i;
            ((float4*)Ws)[r * 8 + (xc4 ^ ((r >> 3) & 7))] = wv[i];
        }
        __syncthreads();

        // ---- compute: 8 float4 steps, swizzled conflict-free reads ----
        #pragma unroll
        for (int d4 = 0; d4 < 8; ++d4) {
            float4 x4[4], w4[8];
            #pragma unroll
            for (int j = 0; j < 4; ++j)
                x4[j] = ((const float4*)Xs)[(te * 4 + j) * 8 + (d4 ^ (te & 7))];
            #pragma unroll
            for (int j = 0; j < 8; ++j)
                w4[j] = ((const float4*)Ws)[(th * 8 + j) * 8 + (d4 ^ (th & 7))];
            #pragma unroll
            for (int ei = 0; ei < 4; ++ei)
                #pragma unroll
                for (int hj = 0; hj < 8; ++hj)
                    C[ei][hj] += dot4(x4[ei], w4[hj]);
        }
    }

    // ---- norms: reduce ssq across the 8 threads sharing a row ----
    #pragma unroll
    for (int m = 4; m >= 1; m >>= 1) {
        ssq0 += __shfl_xor(ssq0, m, 64);
        ssq1 += __shfl_xor(ssq1, m, 64);
    }
    if ((t & 7) == 0) {
        scale_s[xr]      = fminf(1.f, 1.f / fmaxf(sqrtf(ssq0), 1e-12f));
        scale_s[xr + 32] = fminf(1.f, 1.f / fmaxf(sqrtf(ssq1), 1e-12f));
    }
    __syncthreads();

    // ---- epilogue: scale, bf16 store, sc1/sc2 reductions ----
    #pragma unroll
    for (int ei = 0; ei < 4; ++ei) {
        const int e = e0 + te * 4 + ei;
        const float sc = scale_s[te * 4 + ei];
        float acc1 = 0.f, acc2 = 0.f;
        union { uint4 q; ushort_t h[8]; } pk;
        #pragma unroll
        for (int hj = 0; hj < 8; ++hj) {
            float v = C[ei][hj] * sc;
            acc1 += a_s[th * 8 + hj] * v;
            acc2 += a_s[H_ + th * 8 + hj] * v;
            pk.h[hj] = f2bf(v);
        }
        #pragma unroll
        for (int m = 8; m >= 1; m >>= 1) {
            acc1 += __shfl_xor(acc1, m, 64);
            acc2 += __shfl_xor(acc2, m, 64);
        }
        if (e < NENT_) {
            ((uint4*)(P + (size_t)e * H_))[th] = pk.q;
            if (th == 0) { sc1[e] = acc1; sc2[e] = acc2; }
        }
    }
}

// ============================================================================
// main_kernel: one wave per batch item, no LDS, no barriers.
// scores from sc1/sc2 scalar gathers; uv = uc . sum_k alpha_k P[n_k].
// ============================================================================
__launch_bounds__(256)
__global__ void main_kernel(const int* __restrict__ u,
                            const int* __restrict__ t_idx,
                            const int* __restrict__ n_idx,
                            const float* __restrict__ usr,
                            const float* __restrict__ sc1,
                            const float* __restrict__ sc2,
                            const ushort_t* __restrict__ P,
                            float* __restrict__ out) {
    const int wave = threadIdx.x >> 6;
    const int lane = threadIdx.x & 63;
    const int b    = blockIdx.x * 4 + wave;
    const int j    = lane & 31;   // neighbor index / d-chunk index
    const int h    = lane >> 5;   // half: row parity in P loop

    // ---- scores + softmax (lanes duplicated across halves) ----
    const float s0 = sc1[t_idx[b]];
    const int   nk = n_idx[b * K_ + j];
    float s = s0 + sc2[nk];
    s = (s >= 0.f) ? s : 0.2f * s;
    float mx = s;
    #pragma unroll
    for (int m = 16; m >= 1; m >>= 1) mx = fmaxf(mx, __shfl_xor(mx, m, 64));
    float ex = __expf(s - mx);
    float sm = ex;
    #pragma unroll
    for (int m = 16; m >= 1; m >>= 1) sm += __shfl_xor(sm, m, 64);
    const float alpha = ex / sm;

    // ---- user vector -> norm-clipped folded uc fragment (4 floats/lane) ----
    const int uid = u[b];
    float4 u4 = ((const float4*)(usr + (size_t)uid * DIM_))[lane];
    float ss = wred64(dot4(u4, u4));
    float scl = fminf(1.f, 1.f / fmaxf(sqrtf(ss), 1e-12f));
    float4 uc4;
    uc4.x = scl * (__shfl(u4.x, j) + __shfl(u4.x, j + 32));
    uc4.y = scl * (__shfl(u4.y, j) + __shfl(u4.y, j + 32));
    uc4.z = scl * (__shfl(u4.z, j) + __shfl(u4.z, j + 32));
    uc4.w = scl * (__shfl(u4.w, j) + __shfl(u4.w, j + 32));

    // ---- weighted sum of bf16 P rows: 2 rows per iter (one per half) ----
    float4 macc = make_float4(0.f, 0.f, 0.f, 0.f);
    #pragma unroll
    for (int kk = 0; kk < 16; ++kk) {
        const int   myk = 2 * kk + h;
        const float am  = __shfl(alpha, myk);
        const int   nm  = __shfl(nk, myk);
        uint2 v = ((const uint2*)(P + (size_t)nm * H_))[j];
        float p0 = __uint_as_float(v.x << 16);
        float p1 = __uint_as_float(v.x & 0xffff0000u);
        float p2 = __uint_as_float(v.y << 16);
        float p3 = __uint_as_float(v.y & 0xffff0000u);
        macc.x += am * p0;
        macc.y += am * p1;
        macc.z += am * p2;
        macc.w += am * p3;
    }

    const float uv = wred64(dot4(macc, uc4));
    if (lane == 0) out[b] = 1.f / (1.f + __expf(-uv));
}

// ============================================================================
// Fallback (round-1 path) if workspace is too small for the tables.
// ============================================================================
__global__ void precompute_v12(const float* __restrict__ W,
                               const float* __restrict__ a,
                               float* __restrict__ v12) {
    int d = blockIdx.x * blockDim.x + threadIdx.x;
    if (d >= DIM_) return;
    float acc1 = 0.f, acc2 = 0.f;
    for (int h = 0; h < H_; ++h) {
        float w = W[h * DIM_ + d];
        acc1 += a[h] * w;
        acc2 += a[H_ + h] * w;
    }
    v12[d] = acc1;
    v12[DIM_ + d] = acc2;
}

__launch_bounds__(256)
__global__ void gat_main(const int* __restrict__ u,
                         const int* __restrict__ t_idx,
                         const int* __restrict__ n_idx,
                         const float* __restrict__ ent,
                         const float* __restrict__ usr,
                         const float* __restrict__ W,
                         const float* __restrict__ v12,
                         float* __restrict__ out) {
    const int b    = blockIdx.x;
    const int tid  = threadIdx.x;
    const int wave = tid >> 6;
    const int lane = tid & 63;

    __shared__ float xn_s[K_][DIM_];
    __shared__ float scr_s[K_];
    __shared__ float alpha_s[K_];
    __shared__ float uc_s[H_];
    __shared__ float red_s[4];

    const float4 v1_4 = ((const float4*)v12)[lane];
    const float4 v2_4 = ((const float4*)(v12 + DIM_))[lane];

    const int t = t_idx[b];
    float4 t4 = ((const float4*)(ent + (size_t)t * DIM_))[lane];
    float ss_t = wred64(dot4(t4, t4));
    float scl_t = fminf(1.0f, 1.0f / fmaxf(sqrtf(ss_t), 1e-12f));
    float s0 = scl_t * wred64(dot4(t4, v1_4));

    const int uid = u[b];
    float4 u4 = ((const float4*)(usr + (size_t)uid * DIM_))[lane];
    float ss_u = wred64(dot4(u4, u4));
    float scl_u = fminf(1.0f, 1.0f / fmaxf(sqrtf(ss_u), 1e-12f));
    float px = __shfl(u4.x, lane + 32);
    float py = __shfl(u4.y, lane + 32);
    float pz = __shfl(u4.z, lane + 32);
    float pw = __shfl(u4.w, lane + 32);
    if (wave == 0 && lane < 32) {
        float4 uc4;
        uc4.x = scl_u * (u4.x + px);
        uc4.y = scl_u * (u4.y + py);
        uc4.z = scl_u * (u4.z + pz);
        uc4.w = scl_u * (u4.w + pw);
        ((float4*)uc_s)[lane] = uc4;
    }

    for (int kk = 0; kk < 8; ++kk) {
        const int k   = wave * 8 + kk;
        const int idx = n_idx[b * K_ + k];
        float4 e4 = ((const float4*)(ent + (size_t)idx * DIM_))[lane];
        float ssk = wred64(dot4(e4, e4));
        float sk  = fminf(1.0f, 1.0f / fmaxf(sqrtf(ssk), 1e-12f));
        float dv2 = wred64(dot4(e4, v2_4));
        float4 xs;
        xs.x = e4.x * sk; xs.y = e4.y * sk; xs.z = e4.z * sk; xs.w = e4.w * sk;
        ((float4*)xn_s[k])[lane] = xs;
        if (lane == 0) {
            float sc = s0 + sk * dv2;
            scr_s[k] = (sc >= 0.f) ? sc : 0.2f * sc;
        }
    }
    __syncthreads();

    if (tid < 32) {
        float e = scr_s[tid];
        float mx = e;
        #pragma unroll
        for (int m = 16; m >= 1; m >>= 1) mx = fmaxf(mx, __shfl_xor(mx, m, 64));
        float ex = expf(e - mx);
        float sm = ex;
        #pragma unroll
        for (int m = 16; m >= 1; m >>= 1) sm += __shfl_xor(sm, m, 64);
        alpha_s[tid] = ex / sm;
    }
    __syncthreads();

    float m_d = 0.f;
    #pragma unroll
    for (int k = 0; k < K_; ++k) m_d += alpha_s[k] * xn_s[k][tid];

    const float* wcol = W + tid;
    float acc = 0.f;
    #pragma unroll 4
    for (int hh = 0; hh < H_; ++hh) acc += uc_s[hh] * wcol[(size_t)hh * DIM_];

    float p = wred64(acc * m_d);
    if (lane == 0) red_s[wave] = p;
    __syncthreads();
    if (tid == 0) {
        float uv = red_s[0] + red_s[1] + red_s[2] + red_s[3];
        out[b] = 1.0f / (1.0f + expf(-uv));
    }
}

extern "C" void kernel_launch(void* const* d_in, const int* in_sizes, int n_in,
                              void* d_out, int out_size, void* d_ws, size_t ws_size,
                              hipStream_t stream) {
    const int*   u     = (const int*)d_in[0];
    const int*   t_idx = (const int*)d_in[1];
    const int*   n_idx = (const int*)d_in[2];
    const float* ent   = (const float*)d_in[3];
    const float* usr   = (const float*)d_in[4];
    const float* W     = (const float*)d_in[5];
    const float* a     = (const float*)d_in[6];
    float*       out   = (float*)d_out;

    // ws layout: sc1 [100000 f32] | sc2 [100000 f32] | P [100000*128 bf16]
    const size_t SC1_OFF = 0;
    const size_t SC2_OFF = (size_t)NENT_ * 4;
    const size_t P_OFF   = (size_t)NENT_ * 8;
    const size_t NEED    = P_OFF + (size_t)NENT_ * H_ * 2;

    if (ws_size >= NEED) {
        float*    sc1 = (float*)((char*)d_ws + SC1_OFF);
        float*    sc2 = (float*)((char*)d_ws + SC2_OFF);
        ushort_t* P   = (ushort_t*)((char*)d_ws + P_OFF);

        hipLaunchKernelGGL(proj_kernel, dim3((NENT_ + 63) / 64), dim3(256), 0, stream,
                           ent, W, a, sc1, sc2, P);
        hipLaunchKernelGGL(main_kernel, dim3(B_ / 4), dim3(256), 0, stream,
                           u, t_idx, n_idx, usr, sc1, sc2, P, out);
    } else {
        float* v12 = (float*)d_ws;   // 512 floats
        hipLaunchKernelGGL(precompute_v12, dim3(1), dim3(256), 0, stream, W, a, v12);
        hipLaunchKernelGGL(gat_main, dim3(B_), dim3(256), 0, stream,
                           u, t_idx, n_idx, ent, usr, W, v12, out);
    }
}

// Round 3
// 237.528 us; speedup vs baseline: 2.1498x; 2.0054x over previous
//
#include <hip/hip_runtime.h>
#include <math.h>

#define B_    20000
#define K_    32
#define DIM_  256
#define H_    128
#define NENT_ 100000

typedef unsigned int   uint_t;
typedef unsigned short ushort_t;
typedef __attribute__((ext_vector_type(8))) short bf16x8;
typedef __attribute__((ext_vector_type(4))) float f32x4;

__device__ __forceinline__ float dot4(float4 a, float4 b) {
    return a.x * b.x + a.y * b.y + a.z * b.z + a.w * b.w;
}

__device__ __forceinline__ float wred64(float v) {
    #pragma unroll
    for (int m = 32; m >= 1; m >>= 1) v += __shfl_xor(v, m, 64);
    return v;
}

__device__ __forceinline__ ushort_t f2bf(float f) {
    uint_t x = __float_as_uint(f);
    uint_t r = (x + 0x7fffu + ((x >> 16) & 1u)) >> 16;   // RNE
    return (ushort_t)r;
}

__device__ __forceinline__ uint_t pack2(float lo, float hi) {
    return (uint_t)f2bf(lo) | ((uint_t)f2bf(hi) << 16);
}

// ============================================================================
// proj_mfma: P[e][h] = scale_e * (ent[e] . W[h]), bf16; sc1/sc2 = a1/a2 . P[e]
// Computed as C^T: MFMA A = W (rows=h), B = X (cols=e) -> lane holds 4
// consecutive h per e. Block tile 128e x 128h, K-step 64, 4 waves (2h x 2e).
// LDS [row][64] bf16, XOR-swizzled (byte ^= (row&7)<<4) -> conflict-free b128.
// ============================================================================
__launch_bounds__(256)
__global__ void proj_mfma(const float* __restrict__ ent,
                          const float* __restrict__ Wm,
                          const float* __restrict__ av,
                          float* __restrict__ sc1,
                          float* __restrict__ sc2,
                          ushort_t* __restrict__ P) {
    __shared__ short Xs[128 * 64];    // 16 KB
    __shared__ short Ws[128 * 64];    // 16 KB
    __shared__ float ssq_s[128];
    __shared__ float scale_s[128];
    __shared__ float a_s[256];
    __shared__ float sc1h[2][128];
    __shared__ float sc2h[2][128];

    const int t    = threadIdx.x;
    const int gb   = blockIdx.x * 128;
    const int lane = t & 63;
    const int w    = t >> 6;
    const int h0   = (w & 1) * 64;    // wave's h-range
    const int e0   = (w >> 1) * 64;   // wave's e-range
    const int l15  = lane & 15;
    const int l4   = lane >> 4;

    a_s[t] = av[t];

    const int srow = t >> 3;          // 0..31 (staging row within pass)
    const int sch  = t & 7;           // 8-float chunk within 64-d K-step

    float sq[4] = {0.f, 0.f, 0.f, 0.f};
    f32x4 acc[4][4];
    #pragma unroll
    for (int i = 0; i < 4; ++i)
        #pragma unroll
        for (int j = 0; j < 4; ++j)
            acc[i][j] = (f32x4){0.f, 0.f, 0.f, 0.f};

    for (int ks = 0; ks < 4; ++ks) {
        // ---- global loads (coalesced 256B/row-chunk) ----
        float4 xv[4][2], wv[4][2];
        #pragma unroll
        for (int p = 0; p < 4; ++p) {
            const int row = p * 32 + srow;
            const float* xp = ent + (size_t)min(gb + row, NENT_ - 1) * DIM_ + ks * 64 + sch * 8;
            xv[p][0] = ((const float4*)xp)[0];
            xv[p][1] = ((const float4*)xp)[1];
            const float* wp = Wm + (size_t)row * DIM_ + ks * 64 + sch * 8;
            wv[p][0] = ((const float4*)wp)[0];
            wv[p][1] = ((const float4*)wp)[1];
        }
        __syncthreads();   // previous compute done reading LDS
        #pragma unroll
        for (int p = 0; p < 4; ++p) {
            const int row = p * 32 + srow;
            sq[p] += dot4(xv[p][0], xv[p][0]) + dot4(xv[p][1], xv[p][1]);
            const int off = (row * 128 + sch * 16) ^ ((row & 7) << 4);
            union { bf16x8 v; ushort_t u[8]; } px, pw;
            #pragma unroll
            for (int q = 0; q < 4; ++q) {
                px.u[q]     = f2bf(((const float*)&xv[p][0])[q]);
                px.u[q + 4] = f2bf(((const float*)&xv[p][1])[q]);
                pw.u[q]     = f2bf(((const float*)&wv[p][0])[q]);
                pw.u[q + 4] = f2bf(((const float*)&wv[p][1])[q]);
            }
            *(bf16x8*)((char*)Xs + off) = px.v;
            *(bf16x8*)((char*)Ws + off) = pw.v;
        }
        __syncthreads();
        // ---- MFMA: 2 K-chunks of 32 ----
        #pragma unroll
        for (int kk = 0; kk < 2; ++kk) {
            bf16x8 af[4], bf[4];
            #pragma unroll
            for (int i = 0; i < 4; ++i) {
                const int hrow = h0 + i * 16 + l15;
                const int hoff = (hrow * 128 + kk * 64 + l4 * 16) ^ ((hrow & 7) << 4);
                af[i] = *(const bf16x8*)((const char*)Ws + hoff);
                const int erow = e0 + i * 16 + l15;
                const int eoff = (erow * 128 + kk * 64 + l4 * 16) ^ ((erow & 7) << 4);
                bf[i] = *(const bf16x8*)((const char*)Xs + eoff);
            }
            #pragma unroll
            for (int hi = 0; hi < 4; ++hi)
                #pragma unroll
                for (int ej = 0; ej < 4; ++ej)
                    acc[hi][ej] = __builtin_amdgcn_mfma_f32_16x16x32_bf16(
                        af[hi], bf[ej], acc[hi][ej], 0, 0, 0);
        }
    }

    // ---- row norms: reduce over the 8 threads sharing a row ----
    #pragma unroll
    for (int p = 0; p < 4; ++p) {
        float v = sq[p];
        v += __shfl_xor(v, 1, 64);
        v += __shfl_xor(v, 2, 64);
        v += __shfl_xor(v, 4, 64);
        if ((t & 7) == 0) ssq_s[p * 32 + srow] = v;
    }
    __syncthreads();
    if (t < 128) scale_s[t] = fminf(1.f, 1.f / fmaxf(sqrtf(ssq_s[t]), 1e-12f));
    __syncthreads();

    // ---- epilogue: scale, bf16 store (4 consecutive h per reg), sc1/sc2 ----
    #pragma unroll
    for (int ej = 0; ej < 4; ++ej) {
        const int   eloc = e0 + ej * 16 + l15;
        const int   eg   = gb + eloc;
        const float scl  = scale_s[eloc];
        float s1 = 0.f, s2 = 0.f;
        #pragma unroll
        for (int hi = 0; hi < 4; ++hi) {
            const int hbase = h0 + hi * 16 + l4 * 4;
            const float4 a1v = *(const float4*)(a_s + hbase);
            const float4 a2v = *(const float4*)(a_s + H_ + hbase);
            const f32x4 v = acc[hi][ej];
            const float v0 = v[0] * scl, v1 = v[1] * scl, v2 = v[2] * scl, v3 = v[3] * scl;
            s1 += a1v.x * v0 + a1v.y * v1 + a1v.z * v2 + a1v.w * v3;
            s2 += a2v.x * v0 + a2v.y * v1 + a2v.z * v2 + a2v.w * v3;
            if (eg < NENT_) {
                uint2 pk;
                pk.x = pack2(v0, v1);
                pk.y = pack2(v2, v3);
                *(uint2*)(P + (size_t)eg * H_ + hbase) = pk;
            }
        }
        s1 += __shfl_xor(s1, 16, 64);
        s1 += __shfl_xor(s1, 32, 64);
        s2 += __shfl_xor(s2, 16, 64);
        s2 += __shfl_xor(s2, 32, 64);
        if (lane < 16) {
            const int idx = e0 + ej * 16 + lane;
            sc1h[w & 1][idx] = s1;
            sc2h[w & 1][idx] = s2;
        }
    }
    __syncthreads();
    if (t < 128) {
        const int eg = gb + t;
        if (eg < NENT_) {
            sc1[eg] = sc1h[0][t] + sc1h[1][t];
            sc2[eg] = sc2h[0][t] + sc2h[1][t];
        }
    }
}

// ============================================================================
// main_kernel: one wave per batch item. 16-B P gathers (4 rows in flight/iter).
// ============================================================================
__launch_bounds__(256)
__global__ void main_kernel(const int* __restrict__ u,
                            const int* __restrict__ t_idx,
                            const int* __restrict__ n_idx,
                            const float* __restrict__ usr,
                            const float* __restrict__ sc1,
                            const float* __restrict__ sc2,
                            const ushort_t* __restrict__ P,
                            float* __restrict__ out) {
    const int wave = threadIdx.x >> 6;
    const int lane = threadIdx.x & 63;
    const int b    = blockIdx.x * 4 + wave;
    const int j    = lane & 31;
    const int q    = lane >> 4;    // row-group within gather iter
    const int c    = lane & 15;    // 16-B chunk -> h = 8c..8c+7

    // ---- scores + softmax (duplicated across wave halves) ----
    const float s0 = sc1[t_idx[b]];
    const int   nk = n_idx[b * K_ + j];
    float s = s0 + sc2[nk];
    s = (s >= 0.f) ? s : 0.2f * s;
    float mx = s;
    #pragma unroll
    for (int m = 16; m >= 1; m >>= 1) mx = fmaxf(mx, __shfl_xor(mx, m, 64));
    float ex = __expf(s - mx);
    float sm = ex;
    #pragma unroll
    for (int m = 16; m >= 1; m >>= 1) sm += __shfl_xor(sm, m, 64);
    const float alpha = ex / sm;

    // ---- user: norm over full row, folded fragment for h = 8c..8c+7 ----
    const int uid = u[b];
    const float* ub = usr + (size_t)uid * DIM_;
    float4 u4 = ((const float4*)ub)[lane];
    float ss = wred64(dot4(u4, u4));
    float scl = fminf(1.f, 1.f / fmaxf(sqrtf(ss), 1e-12f));
    float4 ua0 = *(const float4*)(ub + 8 * c);
    float4 ua1 = *(const float4*)(ub + 8 * c + 4);
    float4 ub0 = *(const float4*)(ub + H_ + 8 * c);
    float4 ub1 = *(const float4*)(ub + H_ + 8 * c + 4);
    float uc[8];
    uc[0] = scl * (ua0.x + ub0.x); uc[1] = scl * (ua0.y + ub0.y);
    uc[2] = scl * (ua0.z + ub0.z); uc[3] = scl * (ua0.w + ub0.w);
    uc[4] = scl * (ua1.x + ub1.x); uc[5] = scl * (ua1.y + ub1.y);
    uc[6] = scl * (ua1.z + ub1.z); uc[7] = scl * (ua1.w + ub1.w);

    // ---- weighted sum of bf16 P rows: 4 rows per iter via uint4 ----
    float macc[8];
    #pragma unroll
    for (int i = 0; i < 8; ++i) macc[i] = 0.f;
    #pragma unroll
    for (int i = 0; i < 8; ++i) {
        const int   k  = i * 4 + q;
        const float am = __shfl(alpha, k);
        const int   nm = __shfl(nk, k);
        uint4 v = *(const uint4*)((const char*)P + (size_t)nm * 256 + c * 16);
        macc[0] += am * __uint_as_float(v.x << 16);
        macc[1] += am * __uint_as_float(v.x & 0xffff0000u);
        macc[2] += am * __uint_as_float(v.y << 16);
        macc[3] += am * __uint_as_float(v.y & 0xffff0000u);
        macc[4] += am * __uint_as_float(v.z << 16);
        macc[5] += am * __uint_as_float(v.z & 0xffff0000u);
        macc[6] += am * __uint_as_float(v.w << 16);
        macc[7] += am * __uint_as_float(v.w & 0xffff0000u);
    }
    // per-lane partial dot (uc depends only on c), then one scalar reduce
    float sp = 0.f;
    #pragma unroll
    for (int i = 0; i < 8; ++i) sp += uc[i] * macc[i];
    sp = wred64(sp);
    if (lane == 0) out[b] = 1.f / (1.f + __expf(-sp));
}

// ============================================================================
// Fallback (round-1 path) if workspace is too small for the tables.
// ============================================================================
__global__ void precompute_v12(const float* __restrict__ W,
                               const float* __restrict__ a,
                               float* __restrict__ v12) {
    int d = blockIdx.x * blockDim.x + threadIdx.x;
    if (d >= DIM_) return;
    float acc1 = 0.f, acc2 = 0.f;
    for (int h = 0; h < H_; ++h) {
        float w = W[h * DIM_ + d];
        acc1 += a[h] * w;
        acc2 += a[H_ + h] * w;
    }
    v12[d] = acc1;
    v12[DIM_ + d] = acc2;
}

__launch_bounds__(256)
__global__ void gat_main(const int* __restrict__ u,
                         const int* __restrict__ t_idx,
                         const int* __restrict__ n_idx,
                         const float* __restrict__ ent,
                         const float* __restrict__ usr,
                         const float* __restrict__ W,
                         const float* __restrict__ v12,
                         float* __restrict__ out) {
    const int b    = blockIdx.x;
    const int tid  = threadIdx.x;
    const int wave = tid >> 6;
    const int lane = tid & 63;

    __shared__ float xn_s[K_][DIM_];
    __shared__ float scr_s[K_];
    __shared__ float alpha_s[K_];
    __shared__ float uc_s[H_];
    __shared__ float red_s[4];

    const float4 v1_4 = ((const float4*)v12)[lane];
    const float4 v2_4 = ((const float4*)(v12 + DIM_))[lane];

    const int t = t_idx[b];
    float4 t4 = ((const float4*)(ent + (size_t)t * DIM_))[lane];
    float ss_t = wred64(dot4(t4, t4));
    float scl_t = fminf(1.0f, 1.0f / fmaxf(sqrtf(ss_t), 1e-12f));
    float s0 = scl_t * wred64(dot4(t4, v1_4));

    const int uid = u[b];
    float4 u4 = ((const float4*)(usr + (size_t)uid * DIM_))[lane];
    float ss_u = wred64(dot4(u4, u4));
    float scl_u = fminf(1.0f, 1.0f / fmaxf(sqrtf(ss_u), 1e-12f));
    float px = __shfl(u4.x, lane + 32);
    float py = __shfl(u4.y, lane + 32);
    float pz = __shfl(u4.z, lane + 32);
    float pw = __shfl(u4.w, lane + 32);
    if (wave == 0 && lane < 32) {
        float4 uc4;
        uc4.x = scl_u * (u4.x + px);
        uc4.y = scl_u * (u4.y + py);
        uc4.z = scl_u * (u4.z + pz);
        uc4.w = scl_u * (u4.w + pw);
        ((float4*)uc_s)[lane] = uc4;
    }

    for (int kk = 0; kk < 8; ++kk) {
        const int k   = wave * 8 + kk;
        const int idx = n_idx[b * K_ + k];
        float4 e4 = ((const float4*)(ent + (size_t)idx * DIM_))[lane];
        float ssk = wred64(dot4(e4, e4));
        float sk  = fminf(1.0f, 1.0f / fmaxf(sqrtf(ssk), 1e-12f));
        float dv2 = wred64(dot4(e4, v2_4));
        float4 xs;
        xs.x = e4.x * sk; xs.y = e4.y * sk; xs.z = e4.z * sk; xs.w = e4.w * sk;
        ((float4*)xn_s[k])[lane] = xs;
        if (lane == 0) {
            float sc = s0 + sk * dv2;
            scr_s[k] = (sc >= 0.f) ? sc : 0.2f * sc;
        }
    }
    __syncthreads();

    if (tid < 32) {
        float e = scr_s[tid];
        float mx = e;
        #pragma unroll
        for (int m = 16; m >= 1; m >>= 1) mx = fmaxf(mx, __shfl_xor(mx, m, 64));
        float ex = expf(e - mx);
        float sm = ex;
        #pragma unroll
        for (int m = 16; m >= 1; m >>= 1) sm += __shfl_xor(sm, m, 64);
        alpha_s[tid] = ex / sm;
    }
    __syncthreads();

    float m_d = 0.f;
    #pragma unroll
    for (int k = 0; k < K_; ++k) m_d += alpha_s[k] * xn_s[k][tid];

    const float* wcol = W + tid;
    float acc = 0.f;
    #pragma unroll 4
    for (int hh = 0; hh < H_; ++hh) acc += uc_s[hh] * wcol[(size_t)hh * DIM_];

    float p = wred64(acc * m_d);
    if (lane == 0) red_s[wave] = p;
    __syncthreads();
    if (tid == 0) {
        float uv = red_s[0] + red_s[1] + red_s[2] + red_s[3];
        out[b] = 1.0f / (1.0f + expf(-uv));
    }
}

extern "C" void kernel_launch(void* const* d_in, const int* in_sizes, int n_in,
                              void* d_out, int out_size, void* d_ws, size_t ws_size,
                              hipStream_t stream) {
    const int*   u     = (const int*)d_in[0];
    const int*   t_idx = (const int*)d_in[1];
    const int*   n_idx = (const int*)d_in[2];
    const float* ent   = (const float*)d_in[3];
    const float* usr   = (const float*)d_in[4];
    const float* W     = (const float*)d_in[5];
    const float* a     = (const float*)d_in[6];
    float*       out   = (float*)d_out;

    // ws layout: sc1 [100000 f32] | sc2 [100000 f32] | P [100000*128 bf16]
    const size_t SC1_OFF = 0;
    const size_t SC2_OFF = (size_t)NENT_ * 4;
    const size_t P_OFF   = (size_t)NENT_ * 8;
    const size_t NEED    = P_OFF + (size_t)NENT_ * H_ * 2;

    if (ws_size >= NEED) {
        float*    sc1 = (float*)((char*)d_ws + SC1_OFF);
        float*    sc2 = (float*)((char*)d_ws + SC2_OFF);
        ushort_t* P   = (ushort_t*)((char*)d_ws + P_OFF);

        hipLaunchKernelGGL(proj_mfma, dim3((NENT_ + 127) / 128), dim3(256), 0, stream,
                           ent, W, a, sc1, sc2, P);
        hipLaunchKernelGGL(main_kernel, dim3(B_ / 4), dim3(256), 0, stream,
                           u, t_idx, n_idx, usr, sc1, sc2, P, out);
    } else {
        float* v12 = (float*)d_ws;   // 512 floats
        hipLaunchKernelGGL(precompute_v12, dim3(1), dim3(256), 0, stream, W, a, v12);
        hipLaunchKernelGGL(gat_main, dim3(B_), dim3(256), 0, stream,
                           u, t_idx, n_idx, ent, usr, W, v12, out);
    }
}